// Round 1
// 531.671 us; speedup vs baseline: 1.4873x; 1.4873x over previous
//
#include <hip/hip_runtime.h>
#include <math.h>

#define EMBED   2048
#define NEXP    64
#define BATCHN  16384
#define RT      16              // rows per block (per wave: 16 rows x 1 expert-lane)
#define NT_A    256
#define NT_B    256
#define MTILE_B 32
#define MARGIN_THRESH 4e-4f     // fp32 logit error tail ~1e-5; 40x safety margin

// ---------------- Kernel 0: pack W[e][k] -> Wt4[kc][e][4] ----------------
// lane=expert layout: a wave's 64 lanes read one contiguous 1KB block per 4-k chunk.
__global__ __launch_bounds__(256)
void pack_w_kernel(const float* __restrict__ W, float* __restrict__ Wt)
{
    const int g  = blockIdx.x * 256 + threadIdx.x;   // 32768 = 512 kc * 64 e
    const int e  = g & 63;
    const int kc = g >> 6;
    const float4 w = *(const float4*)(W + (size_t)e * EMBED + kc * 4);
    *(float4*)(Wt + (size_t)(kc * 64 + e) * 4) = w;   // consecutive g -> consecutive float4: coalesced store
}

// ---------------- Kernel A: lane=expert GEMM + fused top-2 ----------------
// Each block: 16 rows. 4 waves split K in interleaved 4-chunk phases (share cache
// lines). Per 4-k chunk per wave: 1 coalesced Wt load + 16 uniform-broadcast x
// loads + 64 FMAs. No barriers in the K-loop; one LDS reduction at the end.
__global__ __launch_bounds__(NT_A, 4)
void gemm_topk_kernel(const float* __restrict__ x, const float* __restrict__ Wt,
                      const float* __restrict__ bias, float* __restrict__ out,
                      int* __restrict__ flags)
{
    __shared__ float sh[3][RT][64];       // waves 1..3 partials, 12 KB, conflict-free
    const int tid  = threadIdx.x;
    const int lane = tid & 63;            // lane = expert
    const int ks   = tid >> 6;            // wave id = K interleave phase
    const int row0 = blockIdx.x * RT;

    // k-chunk index for wave ks at step j: kcg = ks + 4*j
    const float*  xb = x + (size_t)row0 * EMBED + ks * 4;          // + j*16 floats
    const float4* wp = (const float4*)Wt + ks * 64 + lane;         // + j*256 float4

    float acc[RT] = {};
    #pragma unroll 1
    for (int j = 0; j < 128; ++j) {
        const float4 wv = wp[(size_t)j * 256];
        #pragma unroll
        for (int r = 0; r < RT; ++r) {
            const float4 xv = *(const float4*)(xb + (size_t)r * EMBED + j * 16);
            acc[r] += xv.x * wv.x + xv.y * wv.y + xv.z * wv.z + xv.w * wv.w;
        }
    }

    // cross-wave K reduction: waves 1..3 publish, wave 0 accumulates
    if (ks > 0) {
        #pragma unroll
        for (int r = 0; r < RT; ++r) sh[ks - 1][r][lane] = acc[r];
    }
    __syncthreads();
    if (ks != 0) return;

    #pragma unroll
    for (int w = 0; w < 3; ++w)
        #pragma unroll
        for (int r = 0; r < RT; ++r) acc[r] += sh[w][r][lane];

    const float bl = bias[lane];

    #pragma unroll 1
    for (int r = 0; r < RT; ++r) {
        // per-lane sorted triple (top-3 for margin), then 6-step butterfly merge
        float v1 = acc[r] + bl, v2 = -INFINITY, v3 = -INFINITY;
        int   i1 = lane, i2 = 0;
        #pragma unroll
        for (int m = 1; m <= 32; m <<= 1) {
            const float o1  = __shfl_xor(v1, m, 64);
            const int   oi1 = __shfl_xor(i1, m, 64);
            const float o2  = __shfl_xor(v2, m, 64);
            const int   oi2 = __shfl_xor(i2, m, 64);
            const float o3  = __shfl_xor(v3, m, 64);
            if (o1 > v1) {
                float nv2; int ni2; float nv3;
                if (v1 > o2) { nv2 = v1; ni2 = i1;  nv3 = fmaxf(v2, o2); }
                else         { nv2 = o2; ni2 = oi2; nv3 = fmaxf(v1, o3); }
                v1 = o1; i1 = oi1; v2 = nv2; i2 = ni2; v3 = nv3;
            } else {
                if (o1 > v2) { v3 = fmaxf(v2, o2); v2 = o1; i2 = oi1; }
                else         { v3 = fmaxf(v3, o1); }
            }
        }
        if (lane == 0) {
            const int row = row0 + r;
            const float margin = fminf(v1 - v2, v2 - v3);
            flags[row] = (margin < MARGIN_THRESH) ? 1 : 0;   // B overwrites flagged rows
            const float e2  = __expf(v2 - v1);
            const float inv = 1.0f / (1.0f + e2);
            *(float2*)&out[row * 2]              = make_float2(inv, e2 * inv);
            *(float2*)&out[2 * BATCHN + row * 2] = make_float2((float)i1, (float)i2);
        }
    }
}

// ---------------- Kernel B: exact f64 recheck of flagged rows (parallel) ----------------
__global__ __launch_bounds__(NT_B, 2)
void recheck_kernel(const float* __restrict__ x, const float* __restrict__ W,
                    const float* __restrict__ bias, float* __restrict__ out,
                    const int* __restrict__ flags)
{
    __shared__ double sh[NEXP];
    const int tid  = threadIdx.x;
    const int row0 = blockIdx.x * MTILE_B;
    const int e = tid >> 2, q = tid & 3;     // 4 threads per expert, 512-elem K slices

    #pragma unroll 1
    for (int r = 0; r < MTILE_B; ++r) {
        if (flags[row0 + r] == 0) continue;  // uniform branch (same address for all threads)
        const float* xr = x + (size_t)(row0 + r) * EMBED + q * 512;
        const float* wr = W + (size_t)e * EMBED + q * 512;
        double s = 0.0;
        #pragma unroll 4
        for (int k = 0; k < 512; k += 4) {
            const float4 xv = *(const float4*)(xr + k);
            const float4 wv = *(const float4*)(wr + k);
            s += (double)xv.x * (double)wv.x;
            s += (double)xv.y * (double)wv.y;
            s += (double)xv.z * (double)wv.z;
            s += (double)xv.w * (double)wv.w;
        }
        s += __shfl_xor(s, 1, 64);           // reduce the 4 K-slices (contiguous lanes)
        s += __shfl_xor(s, 2, 64);
        if (q == 0) sh[e] = s + (double)bias[e];
        __syncthreads();
        if (tid == 0) {
            double v1 = -1e300, v2 = -1e300; int i1 = 0, i2 = 0;
            for (int ee = 0; ee < NEXP; ++ee) {   // ascending: ties keep lower index
                const double v = sh[ee];
                if (v > v1)      { v2 = v1; i2 = i1; v1 = v; i1 = ee; }
                else if (v > v2) { v2 = v; i2 = ee; }
            }
            const int row = row0 + r;
            const double ex  = exp(v2 - v1);
            const double inv = 1.0 / (1.0 + ex);
            out[row * 2]                  = (float)inv;
            out[row * 2 + 1]              = (float)(ex * inv);
            out[2 * BATCHN + row * 2]     = (float)i1;
            out[2 * BATCHN + row * 2 + 1] = (float)i2;
        }
        __syncthreads();
    }
}

extern "C" void kernel_launch(void* const* d_in, const int* in_sizes, int n_in,
                              void* d_out, int out_size, void* d_ws, size_t ws_size,
                              hipStream_t stream) {
    const float* x = (const float*)d_in[0];
    const float* W = (const float*)d_in[1];
    const float* b = (const float*)d_in[2];
    float* out = (float*)d_out;
    int*   flags = (int*)d_ws;                                     // 64 KB
    float* Wt    = (float*)((char*)d_ws + BATCHN * sizeof(int));   // 512 KB packed W
    pack_w_kernel  <<<dim3((512 * 64) / 256),  dim3(256),  0, stream>>>(W, Wt);
    gemm_topk_kernel<<<dim3(BATCHN / RT),      dim3(NT_A), 0, stream>>>(x, Wt, b, out, flags);
    recheck_kernel <<<dim3(BATCHN / MTILE_B),  dim3(NT_B), 0, stream>>>(x, W, b, out, flags);
}

// Round 3
// 244.718 us; speedup vs baseline: 3.2312x; 2.1726x over previous
//
#include <hip/hip_runtime.h>
#include <math.h>

#define EMBED   2048
#define NEXP    64
#define BATCHN  16384
#define RT      16              // rows per block
#define NT_A    256
#define LCAP    16380           // flag-list capacity (fits in 64KB ws slot)
#define MARGIN_THRESH 4e-4f     // bf16-split logit err ~1e-5 abs; 40x margin

typedef float  f32x4  __attribute__((ext_vector_type(4)));
typedef __bf16 bf16x8 __attribute__((ext_vector_type(8)));

// split fp32 -> bf16 hi + bf16 lo (x ~= hi + lo, residual ~2^-18 |x|)
__device__ __forceinline__ void cvt8(const float4& a, const float4& b,
                                     bf16x8& h, bf16x8& l) {
    float f[8] = {a.x, a.y, a.z, a.w, b.x, b.y, b.z, b.w};
    #pragma unroll
    for (int j = 0; j < 8; ++j) {
        __bf16 hh = (__bf16)f[j];
        h[j] = hh;
        l[j] = (__bf16)(f[j] - (float)hh);   // x - hi exact in fp32
    }
}

// ---------------- Kernel 0: pack W -> hi/lo B-fragment layout, zero flag count ----
// Wt[tile][kc][lane][8]: lane holds col=lane&15, k=(lane>>4)*8+j of k-chunk kc.
// Same (lane>>4, j) -> k mapping used for the A fragments => K-consistent.
__global__ __launch_bounds__(256)
void pack_w_kernel(const float* __restrict__ W, __bf16* __restrict__ Wh,
                   __bf16* __restrict__ Wl, int* __restrict__ flagcnt)
{
    const int g = blockIdx.x * 256 + threadIdx.x;    // 16384 = 4 tiles * 64 kc * 64 lanes
    if (g == 0) *flagcnt = 0;
    const int tile = g >> 12, rem = g & 4095;
    const int kc = rem >> 6, ln = rem & 63;
    const int e = tile * 16 + (ln & 15);
    const int k = kc * 32 + (ln >> 4) * 8;
    const float* wp = W + (size_t)e * EMBED + k;
    float4 a = *(const float4*)wp, b = *(const float4*)(wp + 4);
    bf16x8 h, l;
    cvt8(a, b, h, l);
    *(bf16x8*)(Wh + (size_t)g * 8) = h;              // coalesced 16B stores
    *(bf16x8*)(Wl + (size_t)g * 8) = l;
}

// ---------------- Kernel A: bf16-split MFMA GEMM + fused top-2 ----------------
// 16 rows/block, 4 waves = 4 N-tiles of 16 experts. Per 128-k stage: 256 threads
// load+convert x into LDS A-fragment order (conflict-free b128 write/read,
// double-buffered, 1 barrier/stage); each wave: 4 kc x {2 ds_read_b128 A,
// 2 global dwordx4 B (L2-resident), 3 mfma_16x16x32_bf16}.
__global__ __launch_bounds__(NT_A, 4)
void gemm_topk_kernel(const float* __restrict__ x, const __bf16* __restrict__ Wh,
                      const __bf16* __restrict__ Wl, const float* __restrict__ bias,
                      float* __restrict__ out, int* __restrict__ flagcnt,
                      int* __restrict__ flaglist)
{
    __shared__ __align__(16) __bf16 Ah[2][2048];   // 4 kc * 64 lanes * 8
    __shared__ __align__(16) __bf16 Al[2][2048];
    __shared__ float lg[RT][64];

    const int tid  = threadIdx.x;
    const int lane = tid & 63;
    const int w    = tid >> 6;                     // wave = N-tile = staging kc
    const int row0 = blockIdx.x * RT;

    // x source for this thread's A-fragment slot (8 consecutive floats):
    // row = lane&15, k-chunk = w, k-group = lane>>4
    const float* xr = x + (size_t)(row0 + (lane & 15)) * EMBED + w * 32 + (lane >> 4) * 8;
    const __bf16* whp = Wh + ((size_t)w * 64 * 64 + lane) * 8;   // + kcg*512
    const __bf16* wlp = Wl + ((size_t)w * 64 * 64 + lane) * 8;

    f32x4 acc = {0.f, 0.f, 0.f, 0.f};

    {   // prologue: stage 0
        float4 a = *(const float4*)xr, b = *(const float4*)(xr + 4);
        bf16x8 h, l;
        cvt8(a, b, h, l);
        *(bf16x8*)&Ah[0][tid * 8] = h;
        *(bf16x8*)&Al[0][tid * 8] = l;
    }
    __syncthreads();

    #pragma unroll 1
    for (int s = 0; s < 16; ++s) {
        const int cur = s & 1;
        float4 qa, qb;
        if (s < 15) {                              // prefetch next stage's x
            qa = *(const float4*)(xr + (s + 1) * 128);
            qb = *(const float4*)(xr + (s + 1) * 128 + 4);
        }
        #pragma unroll
        for (int kc = 0; kc < 4; ++kc) {
            bf16x8 ah = *(bf16x8*)&Ah[cur][(kc * 64 + lane) * 8];
            bf16x8 al = *(bf16x8*)&Al[cur][(kc * 64 + lane) * 8];
            bf16x8 bh = *(const bf16x8*)(whp + (size_t)(s * 4 + kc) * 512);
            bf16x8 bl = *(const bf16x8*)(wlp + (size_t)(s * 4 + kc) * 512);
            acc = __builtin_amdgcn_mfma_f32_16x16x32_bf16(ah, bh, acc, 0, 0, 0);
            acc = __builtin_amdgcn_mfma_f32_16x16x32_bf16(ah, bl, acc, 0, 0, 0);
            acc = __builtin_amdgcn_mfma_f32_16x16x32_bf16(al, bh, acc, 0, 0, 0);
        }
        if (s < 15) {
            bf16x8 h, l;
            cvt8(qa, qb, h, l);
            *(bf16x8*)&Ah[cur ^ 1][tid * 8] = h;
            *(bf16x8*)&Al[cur ^ 1][tid * 8] = l;
        }
        __syncthreads();
    }

    // D layout (m89-verified): col = lane&15, row_local = (lane>>4)*4 + reg
    const float bb = bias[w * 16 + (lane & 15)];
    #pragma unroll
    for (int q = 0; q < 4; ++q)
        lg[(lane >> 4) * 4 + q][w * 16 + (lane & 15)] = acc[q] + bb;
    __syncthreads();

    // top-2 (+margin via top-3): wave w handles rows 4w..4w+3, lane = expert
    #pragma unroll 1
    for (int r = 0; r < 4; ++r) {
        const int row_l = w * 4 + r;
        float v1 = lg[row_l][lane], v2 = -INFINITY, v3 = -INFINITY;
        int   i1 = lane, i2 = 0;
        #pragma unroll
        for (int m = 1; m <= 32; m <<= 1) {
            const float o1  = __shfl_xor(v1, m, 64);
            const int   oi1 = __shfl_xor(i1, m, 64);
            const float o2  = __shfl_xor(v2, m, 64);
            const int   oi2 = __shfl_xor(i2, m, 64);
            const float o3  = __shfl_xor(v3, m, 64);
            if (o1 > v1) {
                float nv2; int ni2; float nv3;
                if (v1 > o2) { nv2 = v1; ni2 = i1;  nv3 = fmaxf(v2, o2); }
                else         { nv2 = o2; ni2 = oi2; nv3 = fmaxf(v1, o3); }
                v1 = o1; i1 = oi1; v2 = nv2; i2 = ni2; v3 = nv3;
            } else {
                if (o1 > v2) { v3 = fmaxf(v2, o2); v2 = o1; i2 = oi1; }
                else         { v3 = fmaxf(v3, o1); }
            }
        }
        if (lane == 0) {
            const int row = row0 + row_l;
            const float margin = fminf(v1 - v2, v2 - v3);
            if (margin < MARGIN_THRESH) {
                const int idx = atomicAdd(flagcnt, 1);
                if (idx < LCAP) flaglist[idx] = row;
            }
            const float e2  = __expf(v2 - v1);
            const float inv = 1.0f / (1.0f + e2);
            *(float2*)&out[row * 2]              = make_float2(inv, e2 * inv);
            *(float2*)&out[2 * BATCHN + row * 2] = make_float2((float)i1, (float)i2);
        }
    }
}

// ---------------- Kernel B: exact f64 recheck of flagged rows (compacted list) ----
__global__ __launch_bounds__(256, 2)
void recheck_kernel(const float* __restrict__ x, const float* __restrict__ W,
                    const float* __restrict__ bias, float* __restrict__ out,
                    const int* __restrict__ flagcnt, const int* __restrict__ flaglist)
{
    __shared__ double sh[NEXP];
    const int tid = threadIdx.x;
    const int e = tid >> 2, q = tid & 3;          // 4 threads/expert, 512-elem K slices
    int cnt = *flagcnt;
    if (cnt > LCAP) cnt = LCAP;

    #pragma unroll 1
    for (int i = blockIdx.x; i < cnt; i += gridDim.x) {
        const int row = flaglist[i];
        const float* xr = x + (size_t)row * EMBED + q * 512;
        const float* wr = W + (size_t)e * EMBED + q * 512;
        double s = 0.0;
        #pragma unroll 4
        for (int k = 0; k < 512; k += 4) {
            const float4 xv = *(const float4*)(xr + k);
            const float4 wv = *(const float4*)(wr + k);
            s += (double)xv.x * (double)wv.x;
            s += (double)xv.y * (double)wv.y;
            s += (double)xv.z * (double)wv.z;
            s += (double)xv.w * (double)wv.w;
        }
        s += __shfl_xor(s, 1, 64);                // reduce 4 K-slices (contiguous lanes)
        s += __shfl_xor(s, 2, 64);
        if (q == 0) sh[e] = s + (double)bias[e];
        __syncthreads();
        if (tid == 0) {
            double v1 = -1e300, v2 = -1e300; int i1 = 0, i2 = 0;
            for (int ee = 0; ee < NEXP; ++ee) {   // ascending: ties keep lower index
                const double v = sh[ee];
                if (v > v1)      { v2 = v1; i2 = i1; v1 = v; i1 = ee; }
                else if (v > v2) { v2 = v; i2 = ee; }
            }
            const double ex  = exp(v2 - v1);
            const double inv = 1.0 / (1.0 + ex);
            out[row * 2]                  = (float)inv;
            out[row * 2 + 1]              = (float)(ex * inv);
            out[2 * BATCHN + row * 2]     = (float)i1;
            out[2 * BATCHN + row * 2 + 1] = (float)i2;
        }
        __syncthreads();
    }
}

extern "C" void kernel_launch(void* const* d_in, const int* in_sizes, int n_in,
                              void* d_out, int out_size, void* d_ws, size_t ws_size,
                              hipStream_t stream) {
    const float* x = (const float*)d_in[0];
    const float* W = (const float*)d_in[1];
    const float* b = (const float*)d_in[2];
    float* out = (float*)d_out;
    // ws layout (576KB, same footprint as the previously-passing version):
    //   [0,4)        flag count
    //   [16, 65536)  flag list (LCAP=16380 ints)
    //   [64K, 320K)  Wh  (4 tiles * 64 kc * 64 lanes * 8 bf16 = 256KB)
    //   [320K, 576K) Wl
    int*    flagcnt  = (int*)d_ws;
    int*    flaglist = flagcnt + 4;
    __bf16* Wh = (__bf16*)((char*)d_ws + 65536);
    __bf16* Wl = (__bf16*)((char*)d_ws + 65536 + 262144);
    pack_w_kernel   <<<dim3(64),          dim3(256),  0, stream>>>(W, Wh, Wl, flagcnt);
    gemm_topk_kernel<<<dim3(BATCHN / RT), dim3(NT_A), 0, stream>>>(x, Wh, Wl, b, out, flagcnt, flaglist);
    recheck_kernel  <<<dim3(128),         dim3(256),  0, stream>>>(x, W, b, out, flagcnt, flaglist);
}

// Round 5
// 240.446 us; speedup vs baseline: 3.2886x; 1.0178x over previous
//
#include <hip/hip_runtime.h>
#include <math.h>

#define EMBED   2048
#define NEXP    64
#define BATCHN  16384
#define RT      32              // rows per block (dual A-fragments per wave)
#define NT_A    256
#define LCAP    16380           // flag-list capacity (fits in 64KB ws slot)
#define MARGIN_THRESH 4e-4f     // bf16-split logit err ~1e-5 abs; 40x margin

typedef float  f32x4  __attribute__((ext_vector_type(4)));
typedef __bf16 bf16x8 __attribute__((ext_vector_type(8)));

// split fp32 -> bf16 hi + bf16 lo (x ~= hi + lo, residual ~2^-18 |x|)
__device__ __forceinline__ void cvt8(const float4& a, const float4& b,
                                     bf16x8& h, bf16x8& l) {
    float f[8] = {a.x, a.y, a.z, a.w, b.x, b.y, b.z, b.w};
    #pragma unroll
    for (int j = 0; j < 8; ++j) {
        __bf16 hh = (__bf16)f[j];
        h[j] = hh;
        l[j] = (__bf16)(f[j] - (float)hh);   // x - hi exact in fp32
    }
}

// ---------------- Kernel 0: pack W -> hi/lo B-fragment layout, zero flag count ----
// Wt[tile][kcg][lane][8]: lane holds col=lane&15, k=kcg*32+(lane>>4)*8+j.
// Same (lane>>4, j) -> k mapping used for the A fragments => K-consistent.
// (layout hardware-verified in round 3: absmax identical to the fp32 kernel)
__global__ __launch_bounds__(256)
void pack_w_kernel(const float* __restrict__ W, __bf16* __restrict__ Wh,
                   __bf16* __restrict__ Wl, int* __restrict__ flagcnt)
{
    const int g = blockIdx.x * 256 + threadIdx.x;    // 16384 = 4 tiles * 64 kcg * 64 lanes
    if (g == 0) *flagcnt = 0;
    const int tile = g >> 12, rem = g & 4095;
    const int kc = rem >> 6, ln = rem & 63;
    const int e = tile * 16 + (ln & 15);
    const int k = kc * 32 + (ln >> 4) * 8;
    const float* wp = W + (size_t)e * EMBED + k;
    float4 a = *(const float4*)wp, b = *(const float4*)(wp + 4);
    bf16x8 h, l;
    cvt8(a, b, h, l);
    *(bf16x8*)(Wh + (size_t)g * 8) = h;              // coalesced 16B stores
    *(bf16x8*)(Wl + (size_t)g * 8) = l;
}

// ---------------- Kernel A: bf16-split MFMA GEMM + fused top-2 ----------------
// 32 rows/block, 4 waves = 4 expert tiles; each wave does rows 0-15 AND 16-31
// (two A-fragment pairs per kc -> 6 MFMA per W-load pair: 2x W reuse vs round 3,
// halving W L2 traffic to 256 MB). Per 128-k stage: 256 threads load+convert
// 32x128 of x into LDS A-fragment order (conflict-free b128, double-buffered,
// 1 barrier/stage); grid 512 = 2 blocks/CU co-resident.
__global__ __launch_bounds__(NT_A, 2)
void gemm_topk_kernel(const float* __restrict__ x, const __bf16* __restrict__ Wh,
                      const __bf16* __restrict__ Wl, const float* __restrict__ bias,
                      float* __restrict__ out, int* __restrict__ flagcnt,
                      int* __restrict__ flaglist)
{
    __shared__ __align__(16) __bf16 Ah[2][4096];   // [rh*4+kc][lane][8]
    __shared__ __align__(16) __bf16 Al[2][4096];
    __shared__ float lg[RT][64];

    const int tid  = threadIdx.x;
    const int lane = tid & 63;
    const int w    = tid >> 6;                     // wave = expert tile = staging kc
    const int row0 = blockIdx.x * RT;

    // staging source: rows r0 = row0+(lane&15) (rh=0) and r0+16 (rh=1),
    // k = s*128 + w*32 + (lane>>4)*8
    const float* xr0 = x + (size_t)(row0 + (lane & 15)) * EMBED + w * 32 + (lane >> 4) * 8;
    const float* xr1 = xr0 + (size_t)16 * EMBED;
    const __bf16* whp = Wh + ((size_t)w * 64 * 64 + lane) * 8;   // + kcg*512
    const __bf16* wlp = Wl + ((size_t)w * 64 * 64 + lane) * 8;

    f32x4 acc0 = {0.f, 0.f, 0.f, 0.f};            // rows rh=0
    f32x4 acc1 = {0.f, 0.f, 0.f, 0.f};            // rows rh=1

    {   // prologue: stage 0 (both row-halves)
        bf16x8 h, l;
        cvt8(*(const float4*)xr0, *(const float4*)(xr0 + 4), h, l);
        *(bf16x8*)&Ah[0][tid * 8] = h;
        *(bf16x8*)&Al[0][tid * 8] = l;
        cvt8(*(const float4*)xr1, *(const float4*)(xr1 + 4), h, l);
        *(bf16x8*)&Ah[0][2048 + tid * 8] = h;
        *(bf16x8*)&Al[0][2048 + tid * 8] = l;
    }
    __syncthreads();

    #pragma unroll 1
    for (int s = 0; s < 16; ++s) {
        const int cur = s & 1;
        float4 qa0, qb0, qa1, qb1;
        if (s < 15) {                              // prefetch next stage's x
            qa0 = *(const float4*)(xr0 + (s + 1) * 128);
            qb0 = *(const float4*)(xr0 + (s + 1) * 128 + 4);
            qa1 = *(const float4*)(xr1 + (s + 1) * 128);
            qb1 = *(const float4*)(xr1 + (s + 1) * 128 + 4);
        }
        #pragma unroll
        for (int kc = 0; kc < 4; ++kc) {
            const int ao = (kc * 64 + lane) * 8;
            bf16x8 ah0 = *(bf16x8*)&Ah[cur][ao];
            bf16x8 al0 = *(bf16x8*)&Al[cur][ao];
            bf16x8 ah1 = *(bf16x8*)&Ah[cur][2048 + ao];
            bf16x8 al1 = *(bf16x8*)&Al[cur][2048 + ao];
            bf16x8 bh  = *(const bf16x8*)(whp + (size_t)(s * 4 + kc) * 512);
            bf16x8 bl  = *(const bf16x8*)(wlp + (size_t)(s * 4 + kc) * 512);
            acc0 = __builtin_amdgcn_mfma_f32_16x16x32_bf16(ah0, bh, acc0, 0, 0, 0);
            acc0 = __builtin_amdgcn_mfma_f32_16x16x32_bf16(ah0, bl, acc0, 0, 0, 0);
            acc0 = __builtin_amdgcn_mfma_f32_16x16x32_bf16(al0, bh, acc0, 0, 0, 0);
            acc1 = __builtin_amdgcn_mfma_f32_16x16x32_bf16(ah1, bh, acc1, 0, 0, 0);
            acc1 = __builtin_amdgcn_mfma_f32_16x16x32_bf16(ah1, bl, acc1, 0, 0, 0);
            acc1 = __builtin_amdgcn_mfma_f32_16x16x32_bf16(al1, bh, acc1, 0, 0, 0);
        }
        if (s < 15) {
            bf16x8 h, l;
            cvt8(qa0, qb0, h, l);
            *(bf16x8*)&Ah[cur ^ 1][tid * 8] = h;
            *(bf16x8*)&Al[cur ^ 1][tid * 8] = l;
            cvt8(qa1, qb1, h, l);
            *(bf16x8*)&Ah[cur ^ 1][2048 + tid * 8] = h;
            *(bf16x8*)&Al[cur ^ 1][2048 + tid * 8] = l;
        }
        __syncthreads();
    }

    // D layout (m89-verified): col = lane&15, row_local = (lane>>4)*4 + reg (+16 for rh=1)
    const float bb = bias[w * 16 + (lane & 15)];
    #pragma unroll
    for (int q = 0; q < 4; ++q) {
        lg[(lane >> 4) * 4 + q][w * 16 + (lane & 15)]      = acc0[q] + bb;
        lg[16 + (lane >> 4) * 4 + q][w * 16 + (lane & 15)] = acc1[q] + bb;
    }
    __syncthreads();

    // top-2 (+margin via top-3): wave w handles rows 8w..8w+7, lane = expert
    #pragma unroll 1
    for (int r = 0; r < 8; ++r) {
        const int row_l = w * 8 + r;
        float v1 = lg[row_l][lane], v2 = -INFINITY, v3 = -INFINITY;
        int   i1 = lane, i2 = 0;
        #pragma unroll
        for (int m = 1; m <= 32; m <<= 1) {
            const float o1  = __shfl_xor(v1, m, 64);
            const int   oi1 = __shfl_xor(i1, m, 64);
            const float o2  = __shfl_xor(v2, m, 64);
            const int   oi2 = __shfl_xor(i2, m, 64);
            const float o3  = __shfl_xor(v3, m, 64);
            if (o1 > v1) {
                float nv2; int ni2; float nv3;
                if (v1 > o2) { nv2 = v1; ni2 = i1;  nv3 = fmaxf(v2, o2); }
                else         { nv2 = o2; ni2 = oi2; nv3 = fmaxf(v1, o3); }
                v1 = o1; i1 = oi1; v2 = nv2; i2 = ni2; v3 = nv3;
            } else {
                if (o1 > v2) { v3 = fmaxf(v2, o2); v2 = o1; i2 = oi1; }
                else         { v3 = fmaxf(v3, o1); }
            }
        }
        if (lane == 0) {
            const int row = row0 + row_l;
            const float margin = fminf(v1 - v2, v2 - v3);
            if (margin < MARGIN_THRESH) {
                const int idx = atomicAdd(flagcnt, 1);
                if (idx < LCAP) flaglist[idx] = row;
            }
            const float e2  = __expf(v2 - v1);
            const float inv = 1.0f / (1.0f + e2);
            *(float2*)&out[row * 2]              = make_float2(inv, e2 * inv);
            *(float2*)&out[2 * BATCHN + row * 2] = make_float2((float)i1, (float)i2);
        }
    }
}

// ---------------- Kernel B: exact f64 recheck of flagged rows (compacted list) ----
__global__ __launch_bounds__(256, 2)
void recheck_kernel(const float* __restrict__ x, const float* __restrict__ W,
                    const float* __restrict__ bias, float* __restrict__ out,
                    const int* __restrict__ flagcnt, const int* __restrict__ flaglist)
{
    __shared__ double sh[NEXP];
    const int tid = threadIdx.x;
    const int e = tid >> 2, q = tid & 3;          // 4 threads/expert, 512-elem K slices
    int cnt = *flagcnt;
    if (cnt > LCAP) cnt = LCAP;

    #pragma unroll 1
    for (int i = blockIdx.x; i < cnt; i += gridDim.x) {
        const int row = flaglist[i];
        const float* xr = x + (size_t)row * EMBED + q * 512;
        const float* wr = W + (size_t)e * EMBED + q * 512;
        double s = 0.0;
        #pragma unroll 4
        for (int k = 0; k < 512; k += 4) {
            const float4 xv = *(const float4*)(xr + k);
            const float4 wv = *(const float4*)(wr + k);
            s += (double)xv.x * (double)wv.x;
            s += (double)xv.y * (double)wv.y;
            s += (double)xv.z * (double)wv.z;
            s += (double)xv.w * (double)wv.w;
        }
        s += __shfl_xor(s, 1, 64);                // reduce 4 K-slices (contiguous lanes)
        s += __shfl_xor(s, 2, 64);
        if (q == 0) sh[e] = s + (double)bias[e];
        __syncthreads();
        if (tid == 0) {
            double v1 = -1e300, v2 = -1e300; int i1 = 0, i2 = 0;
            for (int ee = 0; ee < NEXP; ++ee) {   // ascending: ties keep lower index
                const double v = sh[ee];
                if (v > v1)      { v2 = v1; i2 = i1; v1 = v; i1 = ee; }
                else if (v > v2) { v2 = v; i2 = ee; }
            }
            const double ex  = exp(v2 - v1);
            const double inv = 1.0 / (1.0 + ex);
            out[row * 2]                  = (float)inv;
            out[row * 2 + 1]              = (float)(ex * inv);
            out[2 * BATCHN + row * 2]     = (float)i1;
            out[2 * BATCHN + row * 2 + 1] = (float)i2;
        }
        __syncthreads();
    }
}

extern "C" void kernel_launch(void* const* d_in, const int* in_sizes, int n_in,
                              void* d_out, int out_size, void* d_ws, size_t ws_size,
                              hipStream_t stream) {
    const float* x = (const float*)d_in[0];
    const float* W = (const float*)d_in[1];
    const float* b = (const float*)d_in[2];
    float* out = (float*)d_out;
    // ws layout (576KB):
    //   [0,4)        flag count
    //   [16, 65536)  flag list (LCAP=16380 ints)
    //   [64K, 320K)  Wh  (4 tiles * 64 kcg * 64 lanes * 8 bf16 = 256KB)
    //   [320K, 576K) Wl
    int*    flagcnt  = (int*)d_ws;
    int*    flaglist = flagcnt + 4;
    __bf16* Wh = (__bf16*)((char*)d_ws + 65536);
    __bf16* Wl = (__bf16*)((char*)d_ws + 65536 + 262144);
    pack_w_kernel   <<<dim3(64),          dim3(256),  0, stream>>>(W, Wh, Wl, flagcnt);
    gemm_topk_kernel<<<dim3(BATCHN / RT), dim3(NT_A), 0, stream>>>(x, Wh, Wl, b, out, flagcnt, flaglist);
    recheck_kernel  <<<dim3(128),         dim3(256),  0, stream>>>(x, W, b, out, flagcnt, flaglist);
}